// Round 1
// baseline (385.382 us; speedup 1.0000x reference)
//
#include <hip/hip_runtime.h>

#define RES 256
#define NCH 128   // C*F
#define NC  16

// ---------------------------------------------------------------------------
// Transpose grid [3][128][256][256] -> [3][256][256][128] (channels innermost)
// so each bilinear corner's 128 channels are one contiguous 512B run.
// ---------------------------------------------------------------------------
__global__ __launch_bounds__(256) void fg_transpose(
    const float* __restrict__ in, float* __restrict__ out)
{
    __shared__ float tile[32][33];
    const int tx = threadIdx.x;   // 0..31
    const int ty = threadIdx.y;   // 0..7
    const int x0 = blockIdx.x * 32;
    const int q0 = blockIdx.y * 32;
    const int p  = blockIdx.z >> 8;
    const int y  = blockIdx.z & 255;

    #pragma unroll
    for (int r = 0; r < 4; ++r) {
        const int q = q0 + ty + r * 8;
        tile[ty + r * 8][tx] =
            in[(((size_t)p * NCH + q) * RES + y) * RES + (size_t)(x0 + tx)];
    }
    __syncthreads();
    #pragma unroll
    for (int r = 0; r < 4; ++r) {
        const int x = x0 + ty + r * 8;
        out[((((size_t)p * RES + y) * RES) + (size_t)x) * NCH + (size_t)(q0 + tx)] =
            tile[tx][ty + r * 8];
    }
}

__device__ __forceinline__ float reflectf(float v) {
    float r = fabsf(v);
    r = fmodf(r, 510.0f);                 // m = 2*(RES-1)
    return (r > 255.0f) ? (510.0f - r) : r;
}

// ---------------------------------------------------------------------------
// Main kernel: 16 lanes per point; lane c owns output channel c (q = c*8+f).
// TRANS=true reads channel-innermost layout (coalesced 512B per corner).
// ---------------------------------------------------------------------------
template <bool TRANS>
__global__ __launch_bounds__(256) void fg_main(
    const float* __restrict__ coords,
    const float* __restrict__ grid,
    const float* __restrict__ freqs,
    float* __restrict__ out, int n)
{
    const int t = threadIdx.x;
    const int c = t & 15;                       // output channel 0..15
    const int i = blockIdx.x * 16 + (t >> 4);   // point index
    if (i >= n) return;

    // per-lane (fr + 0.5) for q = c*8 + j ; fr = 2^(8*clip(freqs,0,1)) - 1
    float frp[8];
    #pragma unroll
    for (int j = 0; j < 8; ++j) {
        float f = fminf(fmaxf(freqs[c * 8 + j], 0.0f), 1.0f);
        frp[j] = __builtin_amdgcn_exp2f(f * 8.0f) - 0.5f;
    }

    const float c0 = coords[3 * (size_t)i + 0];
    const float c1 = coords[3 * (size_t)i + 1];
    const float c2 = coords[3 * (size_t)i + 2];
    const float pts0 = (c0 + 1.0f) * 127.5f;
    const float pts1 = (c1 + 1.0f) * 127.5f;
    const float pts2 = (c2 + 1.0f) * 127.5f;

    float acc = 0.0f;

    #pragma unroll
    for (int p = 0; p < 3; ++p) {
        // plane 0 samples (y,z); plane 1 (x,z); plane 2 (x,y)
        const float sx = (p == 0) ? pts1 : pts0;
        const float sy = (p == 2) ? pts1 : pts2;
        // basis for slot p uses world-dim p
        const float pp = (p == 0) ? pts0 : ((p == 1) ? pts1 : pts2);

        const float ix = reflectf(sx);
        const float iy = reflectf(sy);
        const float x0f = floorf(ix), y0f = floorf(iy);
        const float wx = ix - x0f, wy = iy - y0f;
        int x0 = (int)x0f; x0 = min(max(x0, 0), RES - 1);
        int y0 = (int)y0f; y0 = min(max(y0, 0), RES - 1);
        const int x1 = min(x0 + 1, RES - 1);
        const int y1 = min(y0 + 1, RES - 1);
        const float w00 = (1.0f - wx) * (1.0f - wy);
        const float w01 = wx * (1.0f - wy);
        const float w10 = (1.0f - wx) * wy;
        const float w11 = wx * wy;
        // phase in revolutions: (pts+0.5)*(fr+0.5)/512  ->  cos(2*pi*rev)
        const float A = (pp + 0.5f) * (1.0f / 512.0f);

        float v00[8], v01[8], v10[8], v11[8];
        if (TRANS) {
            const float* b00 = grid + ((((size_t)p * RES + y0) * RES) + x0) * NCH + c * 8;
            const float* b01 = grid + ((((size_t)p * RES + y0) * RES) + x1) * NCH + c * 8;
            const float* b10 = grid + ((((size_t)p * RES + y1) * RES) + x0) * NCH + c * 8;
            const float* b11 = grid + ((((size_t)p * RES + y1) * RES) + x1) * NCH + c * 8;
            *(float4*)(v00 + 0) = *(const float4*)(b00 + 0);
            *(float4*)(v00 + 4) = *(const float4*)(b00 + 4);
            *(float4*)(v01 + 0) = *(const float4*)(b01 + 0);
            *(float4*)(v01 + 4) = *(const float4*)(b01 + 4);
            *(float4*)(v10 + 0) = *(const float4*)(b10 + 0);
            *(float4*)(v10 + 4) = *(const float4*)(b10 + 4);
            *(float4*)(v11 + 0) = *(const float4*)(b11 + 0);
            *(float4*)(v11 + 4) = *(const float4*)(b11 + 4);
        } else {
            const size_t plane = (size_t)p * NCH * RES * RES;
            const int o00 = y0 * RES + x0, o01 = y0 * RES + x1;
            const int o10 = y1 * RES + x0, o11 = y1 * RES + x1;
            #pragma unroll
            for (int j = 0; j < 8; ++j) {
                const float* gq = grid + plane + (size_t)(c * 8 + j) * (RES * RES);
                v00[j] = gq[o00]; v01[j] = gq[o01];
                v10[j] = gq[o10]; v11[j] = gq[o11];
            }
        }

        #pragma unroll
        for (int j = 0; j < 8; ++j) {
            const float coef = w00 * v00[j] + w01 * v01[j]
                             + w10 * v10[j] + w11 * v11[j];
            const float ph = A * frp[j];
            const float rr = __builtin_amdgcn_fractf(ph);
            acc += coef * __builtin_amdgcn_cosf(rr);
        }
    }

    out[(size_t)i * NC + c] = 2.0f * acc;
}

extern "C" void kernel_launch(void* const* d_in, const int* in_sizes, int n_in,
                              void* d_out, int out_size, void* d_ws, size_t ws_size,
                              hipStream_t stream)
{
    const float* coords = (const float*)d_in[0];
    const float* grid   = (const float*)d_in[1];
    const float* freqs  = (const float*)d_in[2];
    float* out = (float*)d_out;
    const int n = in_sizes[0] / 3;

    const size_t tbytes = (size_t)3 * RES * RES * NCH * sizeof(float);
    const int blocks = (n + 15) / 16;

    if (ws_size >= tbytes) {
        float* gridT = (float*)d_ws;
        dim3 tb(32, 8, 1);
        dim3 tg(RES / 32, NCH / 32, 3 * RES);
        hipLaunchKernelGGL(fg_transpose, tg, tb, 0, stream, grid, gridT);
        hipLaunchKernelGGL((fg_main<true>), dim3(blocks), dim3(256), 0, stream,
                           coords, gridT, freqs, out, n);
    } else {
        hipLaunchKernelGGL((fg_main<false>), dim3(blocks), dim3(256), 0, stream,
                           coords, grid, freqs, out, n);
    }
}

// Round 2
// 271.647 us; speedup vs baseline: 1.4187x; 1.4187x over previous
//
#include <hip/hip_runtime.h>

#define RES 256
#define NCH 128   // C*F
#define NC  16
#define QG  32    // channels per transpose block
#define NPK 64    // packed uint32 per (p,y,x) position = NCH/2

__device__ __forceinline__ unsigned int f32_to_bf16_rne(float f) {
    unsigned int u = __float_as_uint(f);
    return (u + 0x7FFFu + ((u >> 16) & 1u)) >> 16;
}
__device__ __forceinline__ float bf16_lo(unsigned int w) {
    return __uint_as_float(w << 16);
}
__device__ __forceinline__ float bf16_hi(unsigned int w) {
    return __uint_as_float(w & 0xFFFF0000u);
}

// ---------------------------------------------------------------------------
// Transpose+pack: f32 [3][128][256][256] -> bf16-pair uint32 [3][256][256][64]
// One block per (plane, y, 32-channel group): 32 KB read, 16 KB write.
// ---------------------------------------------------------------------------
__global__ __launch_bounds__(256) void fg_transpose_bf16(
    const float* __restrict__ in, unsigned int* __restrict__ out)
{
    __shared__ float tile[QG][RES + 1];   // +1 pad: all accesses <=2-way (free)
    const int tid = threadIdx.x;
    const int qg = blockIdx.x;            // 0..3
    const int y  = blockIdx.y;            // 0..255
    const int p  = blockIdx.z;            // 0..2
    const int q0 = qg * QG;

    const float* src = in + (((size_t)p * NCH + q0) * RES + y) * RES;
    #pragma unroll
    for (int it = 0; it < (QG * RES) / 256; ++it) {   // 32 iters, coalesced rows
        const int lin = it * 256 + tid;
        const int qq = lin >> 8;
        const int x  = lin & 255;
        tile[qq][x] = src[(size_t)qq * (RES * RES) + x];
    }
    __syncthreads();
    unsigned int* dst = out + (((size_t)p * RES + y) * RES) * NPK + (q0 >> 1);
    #pragma unroll
    for (int it = 0; it < (RES * (QG / 2)) / 256; ++it) {  // 16 iters
        const int lin = it * 256 + tid;
        const int qp = lin & 15;          // packed-pair index within group
        const int x  = lin >> 4;
        const unsigned int lo = f32_to_bf16_rne(tile[2 * qp + 0][x]);
        const unsigned int hi = f32_to_bf16_rne(tile[2 * qp + 1][x]);
        dst[(size_t)x * NPK + qp] = lo | (hi << 16);
    }
}

__device__ __forceinline__ float reflectf(float v) {
    float r = fabsf(v);
    r = fmodf(r, 510.0f);                 // m = 2*(RES-1)
    return (r > 255.0f) ? (510.0f - r) : r;
}

// ---------------------------------------------------------------------------
// Main kernel (packed bf16 grid): 16 lanes per point; lane c owns output
// channel c (q = c*8+f). One uint4 (16B) per bilinear corner per lane.
// ---------------------------------------------------------------------------
__global__ __launch_bounds__(256) void fg_main_bf16(
    const float* __restrict__ coords,
    const unsigned int* __restrict__ grid,   // [3][256][256][64]
    const float* __restrict__ freqs,
    float* __restrict__ out, int n)
{
    const int t = threadIdx.x;
    const int c = t & 15;                       // output channel 0..15
    const int i = blockIdx.x * 16 + (t >> 4);   // point index
    if (i >= n) return;

    // per-lane (fr + 0.5) for q = c*8 + j ; fr = 2^(8*clip(freqs,0,1)) - 1
    float frp[8];
    #pragma unroll
    for (int j = 0; j < 8; ++j) {
        float f = fminf(fmaxf(freqs[c * 8 + j], 0.0f), 1.0f);
        frp[j] = __builtin_amdgcn_exp2f(f * 8.0f) - 0.5f;
    }

    const float c0 = coords[3 * (size_t)i + 0];
    const float c1 = coords[3 * (size_t)i + 1];
    const float c2 = coords[3 * (size_t)i + 2];
    const float pts0 = (c0 + 1.0f) * 127.5f;
    const float pts1 = (c1 + 1.0f) * 127.5f;
    const float pts2 = (c2 + 1.0f) * 127.5f;

    float acc = 0.0f;

    #pragma unroll
    for (int p = 0; p < 3; ++p) {
        // plane 0 samples (y,z); plane 1 (x,z); plane 2 (x,y)
        const float sx = (p == 0) ? pts1 : pts0;
        const float sy = (p == 2) ? pts1 : pts2;
        const float pp = (p == 0) ? pts0 : ((p == 1) ? pts1 : pts2);

        const float ix = reflectf(sx);
        const float iy = reflectf(sy);
        const float x0f = floorf(ix), y0f = floorf(iy);
        const float wx = ix - x0f, wy = iy - y0f;
        int x0 = (int)x0f; x0 = min(max(x0, 0), RES - 1);
        int y0 = (int)y0f; y0 = min(max(y0, 0), RES - 1);
        const int x1 = min(x0 + 1, RES - 1);
        const int y1 = min(y0 + 1, RES - 1);
        const float w00 = (1.0f - wx) * (1.0f - wy);
        const float w01 = wx * (1.0f - wy);
        const float w10 = (1.0f - wx) * wy;
        const float w11 = wx * wy;
        // phase in revolutions: (pts+0.5)*(fr+0.5)/512  ->  v_cos(2*pi*rev)
        const float A = (pp + 0.5f) * (1.0f / 512.0f);

        const size_t rowbase = ((size_t)p * RES) * RES;
        const unsigned int* b00 = grid + (rowbase + (size_t)y0 * RES + x0) * NPK + c * 4;
        const unsigned int* b01 = grid + (rowbase + (size_t)y0 * RES + x1) * NPK + c * 4;
        const unsigned int* b10 = grid + (rowbase + (size_t)y1 * RES + x0) * NPK + c * 4;
        const unsigned int* b11 = grid + (rowbase + (size_t)y1 * RES + x1) * NPK + c * 4;
        const uint4 g00 = *(const uint4*)b00;
        const uint4 g01 = *(const uint4*)b01;
        const uint4 g10 = *(const uint4*)b10;
        const uint4 g11 = *(const uint4*)b11;
        const unsigned int w0[4] = {g00.x, g00.y, g00.z, g00.w};
        const unsigned int w1[4] = {g01.x, g01.y, g01.z, g01.w};
        const unsigned int w2[4] = {g10.x, g10.y, g10.z, g10.w};
        const unsigned int w3[4] = {g11.x, g11.y, g11.z, g11.w};

        #pragma unroll
        for (int jj = 0; jj < 4; ++jj) {
            const float clo = w00 * bf16_lo(w0[jj]) + w01 * bf16_lo(w1[jj])
                            + w10 * bf16_lo(w2[jj]) + w11 * bf16_lo(w3[jj]);
            const float chi = w00 * bf16_hi(w0[jj]) + w01 * bf16_hi(w1[jj])
                            + w10 * bf16_hi(w2[jj]) + w11 * bf16_hi(w3[jj]);
            const float rl = __builtin_amdgcn_fractf(A * frp[2 * jj + 0]);
            const float rh = __builtin_amdgcn_fractf(A * frp[2 * jj + 1]);
            acc += clo * __builtin_amdgcn_cosf(rl);
            acc += chi * __builtin_amdgcn_cosf(rh);
        }
    }

    out[(size_t)i * NC + c] = 2.0f * acc;
}

// Fallback (no workspace): direct f32 channel-major gather.
__global__ __launch_bounds__(256) void fg_main_f32(
    const float* __restrict__ coords,
    const float* __restrict__ grid,
    const float* __restrict__ freqs,
    float* __restrict__ out, int n)
{
    const int t = threadIdx.x;
    const int c = t & 15;
    const int i = blockIdx.x * 16 + (t >> 4);
    if (i >= n) return;

    float frp[8];
    #pragma unroll
    for (int j = 0; j < 8; ++j) {
        float f = fminf(fmaxf(freqs[c * 8 + j], 0.0f), 1.0f);
        frp[j] = __builtin_amdgcn_exp2f(f * 8.0f) - 0.5f;
    }
    const float c0 = coords[3 * (size_t)i + 0];
    const float c1 = coords[3 * (size_t)i + 1];
    const float c2 = coords[3 * (size_t)i + 2];
    const float pts0 = (c0 + 1.0f) * 127.5f;
    const float pts1 = (c1 + 1.0f) * 127.5f;
    const float pts2 = (c2 + 1.0f) * 127.5f;
    float acc = 0.0f;
    #pragma unroll
    for (int p = 0; p < 3; ++p) {
        const float sx = (p == 0) ? pts1 : pts0;
        const float sy = (p == 2) ? pts1 : pts2;
        const float pp = (p == 0) ? pts0 : ((p == 1) ? pts1 : pts2);
        const float ix = reflectf(sx);
        const float iy = reflectf(sy);
        const float x0f = floorf(ix), y0f = floorf(iy);
        const float wx = ix - x0f, wy = iy - y0f;
        int x0 = (int)x0f; x0 = min(max(x0, 0), RES - 1);
        int y0 = (int)y0f; y0 = min(max(y0, 0), RES - 1);
        const int x1 = min(x0 + 1, RES - 1);
        const int y1 = min(y0 + 1, RES - 1);
        const float w00 = (1.0f - wx) * (1.0f - wy);
        const float w01 = wx * (1.0f - wy);
        const float w10 = (1.0f - wx) * wy;
        const float w11 = wx * wy;
        const float A = (pp + 0.5f) * (1.0f / 512.0f);
        const size_t plane = (size_t)p * NCH * RES * RES;
        const int o00 = y0 * RES + x0, o01 = y0 * RES + x1;
        const int o10 = y1 * RES + x0, o11 = y1 * RES + x1;
        #pragma unroll
        for (int j = 0; j < 8; ++j) {
            const float* gq = grid + plane + (size_t)(c * 8 + j) * (RES * RES);
            const float coef = w00 * gq[o00] + w01 * gq[o01]
                             + w10 * gq[o10] + w11 * gq[o11];
            const float rr = __builtin_amdgcn_fractf(A * frp[j]);
            acc += coef * __builtin_amdgcn_cosf(rr);
        }
    }
    out[(size_t)i * NC + c] = 2.0f * acc;
}

extern "C" void kernel_launch(void* const* d_in, const int* in_sizes, int n_in,
                              void* d_out, int out_size, void* d_ws, size_t ws_size,
                              hipStream_t stream)
{
    const float* coords = (const float*)d_in[0];
    const float* grid   = (const float*)d_in[1];
    const float* freqs  = (const float*)d_in[2];
    float* out = (float*)d_out;
    const int n = in_sizes[0] / 3;

    const size_t tbytes = (size_t)3 * RES * RES * NPK * sizeof(unsigned int);
    const int blocks = (n + 15) / 16;

    if (ws_size >= tbytes) {
        unsigned int* gridT = (unsigned int*)d_ws;
        hipLaunchKernelGGL(fg_transpose_bf16, dim3(4, RES, 3), dim3(256), 0, stream,
                           grid, gridT);
        hipLaunchKernelGGL(fg_main_bf16, dim3(blocks), dim3(256), 0, stream,
                           coords, gridT, freqs, out, n);
    } else {
        hipLaunchKernelGGL(fg_main_f32, dim3(blocks), dim3(256), 0, stream,
                           coords, grid, freqs, out, n);
    }
}